// Round 1
// baseline (514.812 us; speedup 1.0000x reference)
//
#include <hip/hip_runtime.h>

#define B_ 4
#define C_ 256
#define N_ 4096

typedef short short8 __attribute__((ext_vector_type(8)));
typedef float float4v __attribute__((ext_vector_type(4)));

__device__ inline unsigned short f2b(float x){
  unsigned u = __builtin_bit_cast(unsigned, x);
  u = u + 0x7FFFu + ((u >> 16) & 1u);
  return (unsigned short)(u >> 16);
}

// ---------------- fold BN into weights ----------------
__global__ void fold_w_kernel(const float* __restrict__ wq, const float* __restrict__ wk,
    const float* __restrict__ wv,
    const float* gq, const float* bq, const float* mq, const float* vq,
    const float* gk, const float* bk, const float* mk, const float* vk,
    const float* gv, const float* bv, const float* mv, const float* vv,
    unsigned short* wqb, unsigned short* wkb, unsigned short* wvb,
    float* biasq, float* biask, float* biasv){
  int i = blockIdx.x*256 + threadIdx.x;   // 65536 threads
  int o = i >> 8;
  float sv = gv[o]*rsqrtf(vv[o]+1e-5f);
  wvb[i] = f2b(wv[i]*sv);
  if (i < 32*256){
    int oq = i >> 8;
    float sq = gq[oq]*rsqrtf(vq[oq]+1e-5f);
    wqb[i] = f2b(wq[i]*sq);
    float sk = gk[oq]*rsqrtf(vk[oq]+1e-5f);
    wkb[i] = f2b(wk[i]*sk);
  }
  if (i < 256) biasv[i] = bv[i] - mv[i]*(gv[i]*rsqrtf(vv[i]+1e-5f));
  if (i < 32){
    biasq[i] = bq[i] - mq[i]*(gq[i]*rsqrtf(vq[i]+1e-5f));
    biask[i] = bk[i] - mk[i]*(gk[i]*rsqrtf(vk[i]+1e-5f));
  }
}

// ---------------- bilinear upsample 32x32 -> 64x64 (half-pixel, clamped) ----------------
__global__ void upsample_kernel(const float* __restrict__ x1, float* __restrict__ x1u){
  int idx = blockIdx.x*256 + threadIdx.x;       // B*C*64*64 = 4194304
  int x = idx & 63, y = (idx >> 6) & 63, bc = idx >> 12;
  float fy = 0.5f*y - 0.25f, fx = 0.5f*x - 0.25f;
  float y0f = floorf(fy), x0f = floorf(fx);
  float wy = fy - y0f, wx = fx - x0f;
  int y0 = max(0, min(31, (int)y0f)), y1 = max(0, min(31, (int)y0f + 1));
  int x0 = max(0, min(31, (int)x0f)), x1i = max(0, min(31, (int)x0f + 1));
  const float* s = x1 + (size_t)bc*1024;
  float v00 = s[y0*32+x0], v01 = s[y0*32+x1i];
  float v10 = s[y1*32+x0], v11 = s[y1*32+x1i];
  float v0 = v00 + wx*(v01-v00);
  float v1 = v10 + wx*(v11-v10);
  x1u[idx] = v0 + wy*(v1-v0);
}

// ---------------- transpose [B][C][N] f32 -> [B][N][C] bf16 ----------------
__global__ void transpose_bf_kernel(const float* __restrict__ X, unsigned short* __restrict__ Xt){
  __shared__ float tile[64][65];
  int b = blockIdx.z;
  int c0 = blockIdx.y*64, n0 = blockIdx.x*64;
  int t = threadIdx.x;
  int a = t & 63, q = t >> 6;
  #pragma unroll
  for (int i=0;i<16;i++){
    int c = q + i*4;
    tile[c][a] = X[(size_t)(b*C_ + c0 + c)*N_ + n0 + a];
  }
  __syncthreads();
  #pragma unroll
  for (int i=0;i<16;i++){
    int n = q + i*4;
    Xt[(size_t)(b*N_ + n0 + n)*C_ + c0 + a] = f2b(tile[a][n]);
  }
}

// ---------------- 1x1 conv + bias + lrelu as MFMA GEMM ----------------
// Xt: [B][N][C] bf16 ; Wb: [O][C] bf16 (BN scale folded) ; out: CN? [B][O][N] : [B][N][O]
template<int O, bool CN>
__global__ void conv_mfma_kernel(const unsigned short* __restrict__ Xt,
                                 const unsigned short* __restrict__ Wb,
                                 const float* __restrict__ bias,
                                 unsigned short* __restrict__ out){
  int b = blockIdx.y;
  int t = threadIdx.x, lane = t & 63, w = t >> 6;
  int l15 = lane & 15, g = lane >> 4;
  int m0 = blockIdx.x*64 + w*16;
  const unsigned short* xrow = Xt + (size_t)(b*N_ + m0 + l15)*C_ + g*8;
  short8 a[8];
  #pragma unroll
  for (int kk=0;kk<8;kk++) a[kk] = *(const short8*)(xrow + kk*32);
  #pragma unroll
  for (int ot=0; ot<O/16; ot++){
    int o = ot*16 + l15;
    const unsigned short* wrow = Wb + (size_t)o*C_ + g*8;
    float4v acc = {0.f,0.f,0.f,0.f};
    #pragma unroll
    for (int kk=0;kk<8;kk++){
      short8 bfr = *(const short8*)(wrow + kk*32);
      acc = __builtin_amdgcn_mfma_f32_16x16x32_bf16(a[kk], bfr, acc, 0, 0, 0);
    }
    float bs = bias[o];
    #pragma unroll
    for (int r=0;r<4;r++){
      float y = acc[r] + bs;
      y = y >= 0.f ? y : 0.1f*y;
      int m = m0 + g*4 + r;
      if (CN) out[(size_t)(b*O + o)*N_ + m] = f2b(y);
      else    out[(size_t)(b*N_ + m)*O + o] = f2b(y);
    }
  }
}

// ---------------- fused flash attention + gamma*out + x1u ----------------
// Qb,Kb: [B][N][32] bf16 ; Vb: [B][C][N] bf16 ; out: [B][C][N] f32
__global__ void attn_kernel(const unsigned short* __restrict__ Qb,
                            const unsigned short* __restrict__ Kb,
                            const unsigned short* __restrict__ Vb,
                            const float* __restrict__ x1u,
                            const float* __restrict__ gamma_p,
                            float* __restrict__ out){
  __shared__ unsigned short p_lds[4][16*72];   // per-wave P tile [16m][64n], stride 72 (pad)
  __shared__ float o_lds[64][65];              // epilogue transpose staging (64c chunk)
  int b = blockIdx.y;
  int t = threadIdx.x, lane = t & 63, w = t >> 6;
  int l15 = lane & 15, g = lane >> 4;
  int m0 = blockIdx.x*64 + w*16;

  short8 qf = *(const short8*)(Qb + (size_t)(b*N_ + m0 + l15)*32 + g*8);

  float4v acc[16];
  #pragma unroll
  for (int ct=0;ct<16;ct++) acc[ct] = (float4v){0.f,0.f,0.f,0.f};
  float mrun[4] = {-1e30f,-1e30f,-1e30f,-1e30f};
  float lrun[4] = {0.f,0.f,0.f,0.f};
  unsigned short* pl = p_lds[w];
  const float4v zero4 = {0.f,0.f,0.f,0.f};

  for (int nt=0; nt<64; nt++){
    int n0 = nt*64;
    // S = Q K^T for 64 columns (4 x 16x16 tiles). C layout: col=l15, row=g*4+r
    float4v s[4];
    #pragma unroll
    for (int j=0;j<4;j++){
      short8 kf = *(const short8*)(Kb + (size_t)(b*N_ + n0 + j*16 + l15)*32 + g*8);
      s[j] = __builtin_amdgcn_mfma_f32_16x16x32_bf16(qf, kf, zero4, 0, 0, 0);
    }
    // online softmax over the 64 columns
    float mnew[4], sc[4];
    #pragma unroll
    for (int r=0;r<4;r++){
      float tm = fmaxf(fmaxf(s[0][r], s[1][r]), fmaxf(s[2][r], s[3][r]));
      tm = fmaxf(tm, __shfl_xor(tm, 1));
      tm = fmaxf(tm, __shfl_xor(tm, 2));
      tm = fmaxf(tm, __shfl_xor(tm, 4));
      tm = fmaxf(tm, __shfl_xor(tm, 8));
      mnew[r] = fmaxf(mrun[r], tm);
      sc[r] = __expf(mrun[r] - mnew[r]);
      mrun[r] = mnew[r];
    }
    float rs[4] = {0.f,0.f,0.f,0.f};
    #pragma unroll
    for (int j=0;j<4;j++){
      #pragma unroll
      for (int r=0;r<4;r++){
        float pv = __expf(s[j][r] - mnew[r]);
        rs[r] += pv;
        pl[(g*4+r)*72 + j*16 + l15] = f2b(pv);
      }
    }
    #pragma unroll
    for (int r=0;r<4;r++){
      float x = rs[r];
      x += __shfl_xor(x, 1); x += __shfl_xor(x, 2);
      x += __shfl_xor(x, 4); x += __shfl_xor(x, 8);
      lrun[r] = lrun[r]*sc[r] + x;
    }
    #pragma unroll
    for (int ct=0;ct<16;ct++){
      #pragma unroll
      for (int r=0;r<4;r++) acc[ct][r] *= sc[r];
    }
    // P back out of LDS in A-operand layout: A[m=l15][k=g*8+i], k in [0,64)
    short8 pa0 = *(const short8*)(pl + l15*72 + g*8);
    short8 pa1 = *(const short8*)(pl + l15*72 + 32 + g*8);
    // O += P * V^T ; B operand: lane reads 8 contiguous n from V[c][n]
    const unsigned short* vp = Vb + (size_t)(b*C_ + l15)*N_ + n0 + g*8;
    #pragma unroll
    for (int ct=0;ct<16;ct++){
      const unsigned short* vpc = vp + (size_t)ct*16*N_;
      short8 v0 = *(const short8*)(vpc);
      short8 v1 = *(const short8*)(vpc + 32);
      acc[ct] = __builtin_amdgcn_mfma_f32_16x16x32_bf16(pa0, v0, acc[ct], 0, 0, 0);
      acc[ct] = __builtin_amdgcn_mfma_f32_16x16x32_bf16(pa1, v1, acc[ct], 0, 0, 0);
    }
  }

  float gm = gamma_p[0];
  float inv[4];
  #pragma unroll
  for (int r=0;r<4;r++) inv[r] = 1.f/lrun[r];
  int mth = t & 63, c4 = t >> 6;
  for (int cc=0; cc<4; cc++){
    __syncthreads();
    #pragma unroll
    for (int ct2=0; ct2<4; ct2++){
      int ct = cc*4 + ct2;
      #pragma unroll
      for (int r=0;r<4;r++)
        o_lds[w*16 + g*4 + r][ct2*16 + l15] = acc[ct][r]*inv[r];
    }
    __syncthreads();
    #pragma unroll
    for (int i=0;i<16;i++){
      int cl = c4 + i*4;
      int c = cc*64 + cl;
      size_t gidx = (size_t)(b*C_ + c)*N_ + blockIdx.x*64 + mth;
      out[gidx] = gm*o_lds[mth][cl] + x1u[gidx];
    }
  }
}

extern "C" void kernel_launch(void* const* d_in, const int* in_sizes, int n_in,
                              void* d_out, int out_size, void* d_ws, size_t ws_size,
                              hipStream_t stream){
  (void)in_sizes; (void)n_in; (void)out_size; (void)ws_size;
  const float* x1 = (const float*)d_in[0];
  const float* x2 = (const float*)d_in[1];
  const float* wq = (const float*)d_in[2];
  const float* wk = (const float*)d_in[3];
  const float* wv = (const float*)d_in[4];
  const float* gq = (const float*)d_in[5];
  const float* bq = (const float*)d_in[6];
  const float* mq = (const float*)d_in[7];
  const float* vq = (const float*)d_in[8];
  const float* gk = (const float*)d_in[9];
  const float* bk = (const float*)d_in[10];
  const float* mk = (const float*)d_in[11];
  const float* vk = (const float*)d_in[12];
  const float* gv = (const float*)d_in[13];
  const float* bv = (const float*)d_in[14];
  const float* mv = (const float*)d_in[15];
  const float* vv = (const float*)d_in[16];
  const float* gamma = (const float*)d_in[17];
  float* out = (float*)d_out;

  char* p = (char*)d_ws;
  float* x1u          = (float*)p;          p += (size_t)B_*C_*N_*4;   // 16 MB
  unsigned short* x1t = (unsigned short*)p; p += (size_t)B_*N_*C_*2;   // 8 MB
  unsigned short* x2t = (unsigned short*)p; p += (size_t)B_*N_*C_*2;   // 8 MB
  unsigned short* Qb  = (unsigned short*)p; p += (size_t)B_*N_*32*2;   // 1 MB
  unsigned short* Kb  = (unsigned short*)p; p += (size_t)B_*N_*32*2;   // 1 MB
  unsigned short* Vb  = (unsigned short*)p; p += (size_t)B_*C_*N_*2;   // 8 MB
  unsigned short* wqb = (unsigned short*)p; p += 32*256*2;
  unsigned short* wkb = (unsigned short*)p; p += 32*256*2;
  unsigned short* wvb = (unsigned short*)p; p += 256*256*2;
  float* biasq        = (float*)p;          p += 32*4;
  float* biask        = (float*)p;          p += 32*4;
  float* biasv        = (float*)p;          p += 256*4;

  fold_w_kernel<<<256, 256, 0, stream>>>(wq,wk,wv,gq,bq,mq,vq,gk,bk,mk,vk,gv,bv,mv,vv,
                                         wqb,wkb,wvb,biasq,biask,biasv);
  upsample_kernel<<<16384, 256, 0, stream>>>(x1, x1u);
  transpose_bf_kernel<<<dim3(64,4,4), 256, 0, stream>>>(x1u, x1t);
  transpose_bf_kernel<<<dim3(64,4,4), 256, 0, stream>>>(x2, x2t);
  conv_mfma_kernel<32,false><<<dim3(64,4), 256, 0, stream>>>(x1t, wqb, biasq, Qb);
  conv_mfma_kernel<32,false><<<dim3(64,4), 256, 0, stream>>>(x2t, wkb, biask, Kb);
  conv_mfma_kernel<256,true><<<dim3(64,4), 256, 0, stream>>>(x2t, wvb, biasv, Vb);
  attn_kernel<<<dim3(64,4), 256, 0, stream>>>(Qb, Kb, Vb, x1u, gamma, out);
}

// Round 2
// 310.476 us; speedup vs baseline: 1.6581x; 1.6581x over previous
//
#include <hip/hip_runtime.h>

#define B_ 4
#define C_ 256
#define N_ 4096

typedef short short8 __attribute__((ext_vector_type(8)));
typedef float float4v __attribute__((ext_vector_type(4)));

__device__ inline unsigned short f2b(float x){
  unsigned u = __builtin_bit_cast(unsigned, x);
  u = u + 0x7FFFu + ((u >> 16) & 1u);
  return (unsigned short)(u >> 16);
}

// ---------------- fold BN into weights ----------------
__global__ void fold_w_kernel(const float* __restrict__ wq, const float* __restrict__ wk,
    const float* __restrict__ wv,
    const float* gq, const float* bq, const float* mq, const float* vq,
    const float* gk, const float* bk, const float* mk, const float* vk,
    const float* gv, const float* bv, const float* mv, const float* vv,
    unsigned short* wqb, unsigned short* wkb, unsigned short* wvb,
    float* biasq, float* biask, float* biasv){
  int i = blockIdx.x*256 + threadIdx.x;   // 65536 threads
  int o = i >> 8;
  float sv = gv[o]*rsqrtf(vv[o]+1e-5f);
  wvb[i] = f2b(wv[i]*sv);
  if (i < 32*256){
    int oq = i >> 8;
    float sq = gq[oq]*rsqrtf(vq[oq]+1e-5f);
    wqb[i] = f2b(wq[i]*sq);
    float sk = gk[oq]*rsqrtf(vk[oq]+1e-5f);
    wkb[i] = f2b(wk[i]*sk);
  }
  if (i < 256) biasv[i] = bv[i] - mv[i]*(gv[i]*rsqrtf(vv[i]+1e-5f));
  if (i < 32){
    biasq[i] = bq[i] - mq[i]*(gq[i]*rsqrtf(vq[i]+1e-5f));
    biask[i] = bk[i] - mk[i]*(gk[i]*rsqrtf(vk[i]+1e-5f));
  }
}

// ---------------- bilinear upsample 32x32 -> 64x64 (half-pixel, clamped) ----------------
__global__ void upsample_kernel(const float* __restrict__ x1, float* __restrict__ x1u){
  int idx = blockIdx.x*256 + threadIdx.x;       // B*C*64*64 = 4194304
  int x = idx & 63, y = (idx >> 6) & 63, bc = idx >> 12;
  float fy = 0.5f*y - 0.25f, fx = 0.5f*x - 0.25f;
  float y0f = floorf(fy), x0f = floorf(fx);
  float wy = fy - y0f, wx = fx - x0f;
  int y0 = max(0, min(31, (int)y0f)), y1 = max(0, min(31, (int)y0f + 1));
  int x0 = max(0, min(31, (int)x0f)), x1i = max(0, min(31, (int)x0f + 1));
  const float* s = x1 + (size_t)bc*1024;
  float v00 = s[y0*32+x0], v01 = s[y0*32+x1i];
  float v10 = s[y1*32+x0], v11 = s[y1*32+x1i];
  float v0 = v00 + wx*(v01-v00);
  float v1 = v10 + wx*(v11-v10);
  x1u[idx] = v0 + wy*(v1-v0);
}

// ---------------- transpose [B][C][N] f32 -> [B][N][C] bf16 ----------------
__global__ void transpose_bf_kernel(const float* __restrict__ X, unsigned short* __restrict__ Xt){
  __shared__ float tile[64][65];
  int b = blockIdx.z;
  int c0 = blockIdx.y*64, n0 = blockIdx.x*64;
  int t = threadIdx.x;
  int a = t & 63, q = t >> 6;
  #pragma unroll
  for (int i=0;i<16;i++){
    int c = q + i*4;
    tile[c][a] = X[(size_t)(b*C_ + c0 + c)*N_ + n0 + a];
  }
  __syncthreads();
  #pragma unroll
  for (int i=0;i<16;i++){
    int n = q + i*4;
    Xt[(size_t)(b*N_ + n0 + n)*C_ + c0 + a] = f2b(tile[a][n]);
  }
}

// ---------------- 1x1 conv + bias + lrelu as MFMA GEMM ----------------
template<int O, bool CN>
__global__ void conv_mfma_kernel(const unsigned short* __restrict__ Xt,
                                 const unsigned short* __restrict__ Wb,
                                 const float* __restrict__ bias,
                                 unsigned short* __restrict__ out){
  int b = blockIdx.y;
  int t = threadIdx.x, lane = t & 63, w = t >> 6;
  int l15 = lane & 15, g = lane >> 4;
  int m0 = blockIdx.x*64 + w*16;
  const unsigned short* xrow = Xt + (size_t)(b*N_ + m0 + l15)*C_ + g*8;
  short8 a[8];
  #pragma unroll
  for (int kk=0;kk<8;kk++) a[kk] = *(const short8*)(xrow + kk*32);
  #pragma unroll
  for (int ot=0; ot<O/16; ot++){
    int o = ot*16 + l15;
    const unsigned short* wrow = Wb + (size_t)o*C_ + g*8;
    float4v acc = {0.f,0.f,0.f,0.f};
    #pragma unroll
    for (int kk=0;kk<8;kk++){
      short8 bfr = *(const short8*)(wrow + kk*32);
      acc = __builtin_amdgcn_mfma_f32_16x16x32_bf16(a[kk], bfr, acc, 0, 0, 0);
    }
    float bs = bias[o];
    #pragma unroll
    for (int r=0;r<4;r++){
      float y = acc[r] + bs;
      y = y >= 0.f ? y : 0.1f*y;
      int m = m0 + g*4 + r;
      if (CN) out[(size_t)(b*O + o)*N_ + m] = f2b(y);
      else    out[(size_t)(b*N_ + m)*O + o] = f2b(y);
    }
  }
}

// ---------------- fused flash attention + gamma*out + x1u ----------------
// 16 waves: wm = w&3 (m sub-tile, 16 rows), ng = w>>2 (n-range quarter).
// Qb,Kb: [B][N][32] bf16 ; Vb: [B][C][N] bf16 ; out: [B][C][N] f32
__global__ __launch_bounds__(1024, 3)
void attn_kernel(const unsigned short* __restrict__ Qb,
                 const unsigned short* __restrict__ Kb,
                 const unsigned short* __restrict__ Vb,
                 const float* __restrict__ x1u,
                 const float* __restrict__ gamma_p,
                 float* __restrict__ out){
  __shared__ unsigned short p_lds[16][16*68];  // per-wave P tile [16m][64n], stride 68
  __shared__ float o4[4][64][66];              // per-group partial O chunk [m][64c]
  __shared__ float stats[4][64][2];            // per-group (m, l) per row
  __shared__ float ML[64][2];                  // combined (M, L) per row
  int b = blockIdx.y;
  int t = threadIdx.x, lane = t & 63, w = t >> 6;
  int wm = w & 3, ng = w >> 2;
  int l15 = lane & 15, g = lane >> 4;
  int m0 = blockIdx.x*64 + wm*16;

  short8 qf = *(const short8*)(Qb + (size_t)(b*N_ + m0 + l15)*32 + g*8);

  float4v acc[16];
  #pragma unroll
  for (int ct=0;ct<16;ct++) acc[ct] = (float4v){0.f,0.f,0.f,0.f};
  float mrun[4] = {-1e30f,-1e30f,-1e30f,-1e30f};
  float lrun[4] = {0.f,0.f,0.f,0.f};
  unsigned short* pl = p_lds[w];
  const float4v zero4 = {0.f,0.f,0.f,0.f};

  for (int nt=0; nt<16; nt++){
    int n0 = ng*1024 + nt*64;
    // S = Q K^T for 64 columns. C layout: row g*4+r = m, col l15 = n
    float4v s[4];
    #pragma unroll
    for (int j=0;j<4;j++){
      short8 kf = *(const short8*)(Kb + (size_t)(b*N_ + n0 + j*16 + l15)*32 + g*8);
      s[j] = __builtin_amdgcn_mfma_f32_16x16x32_bf16(qf, kf, zero4, 0, 0, 0);
    }
    // local (per-lane) tile max; defer full reduce+rescale unless needed (exact)
    float tmax[4];
    bool need = false;
    #pragma unroll
    for (int r=0;r<4;r++){
      tmax[r] = fmaxf(fmaxf(s[0][r], s[1][r]), fmaxf(s[2][r], s[3][r]));
      need = need || (tmax[r] > mrun[r] + 8.f);
    }
    if (__any(need)){
      #pragma unroll
      for (int r=0;r<4;r++){
        float tm = tmax[r];
        tm = fmaxf(tm, __shfl_xor(tm, 1));
        tm = fmaxf(tm, __shfl_xor(tm, 2));
        tm = fmaxf(tm, __shfl_xor(tm, 4));
        tm = fmaxf(tm, __shfl_xor(tm, 8));
        float mnew = fmaxf(mrun[r], tm);
        float sc = __expf(mrun[r] - mnew);
        mrun[r] = mnew;
        lrun[r] *= sc;
        #pragma unroll
        for (int ct=0;ct<16;ct++) acc[ct][r] *= sc;
      }
    }
    // P = exp(S - mrun); per-lane partial row sums (cross-lane reduce deferred)
    #pragma unroll
    for (int j=0;j<4;j++){
      #pragma unroll
      for (int r=0;r<4;r++){
        float pv = __expf(s[j][r] - mrun[r]);
        lrun[r] += pv;
        pl[(g*4+r)*68 + j*16 + l15] = f2b(pv);
      }
    }
    // P as A operand: A[m=l15][k in 0..63]
    short8 pa0 = *(const short8*)(pl + l15*68 + g*8);
    short8 pa1 = *(const short8*)(pl + l15*68 + 32 + g*8);
    // O += P * V^T
    const unsigned short* vp = Vb + (size_t)(b*C_ + l15)*N_ + n0 + g*8;
    #pragma unroll
    for (int ct=0;ct<16;ct++){
      const unsigned short* vpc = vp + (size_t)ct*16*N_;
      short8 v0 = *(const short8*)(vpc);
      short8 v1 = *(const short8*)(vpc + 32);
      acc[ct] = __builtin_amdgcn_mfma_f32_16x16x32_bf16(pa0, v0, acc[ct], 0, 0, 0);
      acc[ct] = __builtin_amdgcn_mfma_f32_16x16x32_bf16(pa1, v1, acc[ct], 0, 0, 0);
    }
  }

  // cross-lane l reduce (once), publish per-group stats
  #pragma unroll
  for (int r=0;r<4;r++){
    float x = lrun[r];
    x += __shfl_xor(x, 1); x += __shfl_xor(x, 2);
    x += __shfl_xor(x, 4); x += __shfl_xor(x, 8);
    lrun[r] = x;
  }
  if (l15 == 0){
    #pragma unroll
    for (int r=0;r<4;r++){
      stats[ng][wm*16 + g*4 + r][0] = mrun[r];
      stats[ng][wm*16 + g*4 + r][1] = lrun[r];
    }
  }
  __syncthreads();
  if (t < 64){
    float M = -1e30f;
    #pragma unroll
    for (int q4=0;q4<4;q4++) M = fmaxf(M, stats[q4][t][0]);
    float L = 0.f;
    #pragma unroll
    for (int q4=0;q4<4;q4++) L += stats[q4][t][1]*__expf(stats[q4][t][0]-M);
    ML[t][0] = M; ML[t][1] = L;
  }
  __syncthreads();
  float wsc[4];
  #pragma unroll
  for (int r=0;r<4;r++) wsc[r] = __expf(mrun[r] - ML[wm*16 + g*4 + r][0]);

  float gm = gamma_p[0];
  int m_l = t & 63, cq = t >> 6;
  #pragma unroll
  for (int cc=0; cc<4; cc++){
    // each group writes its weighted partial for 64 c's
    #pragma unroll
    for (int ct2=0; ct2<4; ct2++){
      #pragma unroll
      for (int r=0;r<4;r++)
        o4[ng][wm*16 + g*4 + r][ct2*16 + l15] = acc[cc*4+ct2][r]*wsc[r];
    }
    __syncthreads();
    #pragma unroll
    for (int i=0;i<4;i++){
      int c_l = cq + 16*i;
      float v = o4[0][m_l][c_l] + o4[1][m_l][c_l] + o4[2][m_l][c_l] + o4[3][m_l][c_l];
      size_t gidx = (size_t)(b*C_ + cc*64 + c_l)*N_ + blockIdx.x*64 + m_l;
      out[gidx] = gm*v/ML[m_l][1] + x1u[gidx];
    }
    __syncthreads();
  }
}

extern "C" void kernel_launch(void* const* d_in, const int* in_sizes, int n_in,
                              void* d_out, int out_size, void* d_ws, size_t ws_size,
                              hipStream_t stream){
  (void)in_sizes; (void)n_in; (void)out_size; (void)ws_size;
  const float* x1 = (const float*)d_in[0];
  const float* x2 = (const float*)d_in[1];
  const float* wq = (const float*)d_in[2];
  const float* wk = (const float*)d_in[3];
  const float* wv = (const float*)d_in[4];
  const float* gq = (const float*)d_in[5];
  const float* bq = (const float*)d_in[6];
  const float* mq = (const float*)d_in[7];
  const float* vq = (const float*)d_in[8];
  const float* gk = (const float*)d_in[9];
  const float* bk = (const float*)d_in[10];
  const float* mk = (const float*)d_in[11];
  const float* vk = (const float*)d_in[12];
  const float* gv = (const float*)d_in[13];
  const float* bv = (const float*)d_in[14];
  const float* mv = (const float*)d_in[15];
  const float* vv = (const float*)d_in[16];
  const float* gamma = (const float*)d_in[17];
  float* out = (float*)d_out;

  char* p = (char*)d_ws;
  float* x1u          = (float*)p;          p += (size_t)B_*C_*N_*4;   // 16 MB
  unsigned short* x1t = (unsigned short*)p; p += (size_t)B_*N_*C_*2;   // 8 MB
  unsigned short* x2t = (unsigned short*)p; p += (size_t)B_*N_*C_*2;   // 8 MB
  unsigned short* Qb  = (unsigned short*)p; p += (size_t)B_*N_*32*2;   // 1 MB
  unsigned short* Kb  = (unsigned short*)p; p += (size_t)B_*N_*32*2;   // 1 MB
  unsigned short* Vb  = (unsigned short*)p; p += (size_t)B_*C_*N_*2;   // 8 MB
  unsigned short* wqb = (unsigned short*)p; p += 32*256*2;
  unsigned short* wkb = (unsigned short*)p; p += 32*256*2;
  unsigned short* wvb = (unsigned short*)p; p += 256*256*2;
  float* biasq        = (float*)p;          p += 32*4;
  float* biask        = (float*)p;          p += 32*4;
  float* biasv        = (float*)p;          p += 256*4;

  fold_w_kernel<<<256, 256, 0, stream>>>(wq,wk,wv,gq,bq,mq,vq,gk,bk,mk,vk,gv,bv,mv,vv,
                                         wqb,wkb,wvb,biasq,biask,biasv);
  upsample_kernel<<<16384, 256, 0, stream>>>(x1, x1u);
  transpose_bf_kernel<<<dim3(64,4,4), 256, 0, stream>>>(x1u, x1t);
  transpose_bf_kernel<<<dim3(64,4,4), 256, 0, stream>>>(x2, x2t);
  conv_mfma_kernel<32,false><<<dim3(64,4), 256, 0, stream>>>(x1t, wqb, biasq, Qb);
  conv_mfma_kernel<32,false><<<dim3(64,4), 256, 0, stream>>>(x2t, wkb, biask, Kb);
  conv_mfma_kernel<256,true><<<dim3(64,4), 256, 0, stream>>>(x2t, wvb, biasv, Vb);
  attn_kernel<<<dim3(64,4), 1024, 0, stream>>>(Qb, Kb, Vb, x1u, gamma, out);
}